// Round 1
// baseline (159.302 us; speedup 1.0000x reference)
//
#include <hip/hip_runtime.h>

// LayerHypercube: out[b, f*1024+o] = sum_j x[b, o^(1<<j)] * w[f,j,o] + bias[f,o] + x[b,o]
// B=2048, F=16, O=I=1024, BITS=10. fm is analytic (o ^ (1<<j)) -- not read.
//
// Mapping: wave owns one 64-wide o-chunk (lane <-> o) and 4 feature maps
// (weights in 44 regs/lane). j<6 gather = __shfl_xor within wave; j=6..9
// gather = coalesced load of lane l from chunk c^{1,2,4,8}. Block = 4 waves
// = all 16 f for one chunk (L1 reuse of the 5 x-chunk loads across waves).
// Grid = 16 chunks x 64 batch-tiles (BTILE=32) = 1024 blocks (4/CU).

#define BTILE 32

__global__ __launch_bounds__(256, 4) void hypercube_kernel(
    const float* __restrict__ x,      // [2048][1024]
    const float* __restrict__ w,      // [16][10][1024]
    const float* __restrict__ bias,   // [16][1024]
    float* __restrict__ out)          // [2048][16*1024]
{
    const int lane  = threadIdx.x & 63;
    const int wave  = threadIdx.x >> 6;
    const int chunk = blockIdx.x & 15;   // which 64-wide o-chunk
    const int btile = blockIdx.x >> 4;   // which batch tile
    const int b0    = btile * BTILE;
    const int f0    = wave * 4;          // this wave's 4 feature maps
    const int obase = chunk * 64;
    const int o     = obase + lane;

    // Weights for 4 f's, this lane's o: 40 + 4 regs, loaded once per block.
    float wr[4][10], br[4];
    #pragma unroll
    for (int ff = 0; ff < 4; ++ff) {
        const int f = f0 + ff;
        #pragma unroll
        for (int j = 0; j < 10; ++j)
            wr[ff][j] = w[(f * 10 + j) * 1024 + o];
        br[ff] = bias[f * 1024 + o];
    }

    // Partner-chunk addresses for the high XOR bits (j=6..9):
    // (o ^ 64)  lives at lane l of chunk c^1, etc. (chunk is 64-aligned).
    const int a64  = (chunk ^ 1) * 64 + lane;
    const int a128 = (chunk ^ 2) * 64 + lane;
    const int a256 = (chunk ^ 4) * 64 + lane;
    const int a512 = (chunk ^ 8) * 64 + lane;

    #pragma unroll 2
    for (int bi = 0; bi < BTILE; ++bi) {
        const int b = b0 + bi;
        const float* __restrict__ xb = x + (size_t)b * 1024;

        // 5 coalesced 256B loads per wave (L1/L2-resident x).
        const float x0   = xb[o];
        const float x64  = xb[a64];
        const float x128 = xb[a128];
        const float x256 = xb[a256];
        const float x512 = xb[a512];

        // Low XOR bits (j=0..5): in-wave shuffles, shared by all 4 f's.
        const float s0 = __shfl_xor(x0, 1);
        const float s1 = __shfl_xor(x0, 2);
        const float s2 = __shfl_xor(x0, 4);
        const float s3 = __shfl_xor(x0, 8);
        const float s4 = __shfl_xor(x0, 16);
        const float s5 = __shfl_xor(x0, 32);

        float* __restrict__ ob = out + (size_t)b * (16 * 1024) + obase + lane;
        #pragma unroll
        for (int ff = 0; ff < 4; ++ff) {
            float acc = br[ff] + x0;              // bias + tiled-x term
            acc = fmaf(s0,   wr[ff][0], acc);
            acc = fmaf(s1,   wr[ff][1], acc);
            acc = fmaf(s2,   wr[ff][2], acc);
            acc = fmaf(s3,   wr[ff][3], acc);
            acc = fmaf(s4,   wr[ff][4], acc);
            acc = fmaf(s5,   wr[ff][5], acc);
            acc = fmaf(x64,  wr[ff][6], acc);
            acc = fmaf(x128, wr[ff][7], acc);
            acc = fmaf(x256, wr[ff][8], acc);
            acc = fmaf(x512, wr[ff][9], acc);
            ob[(size_t)(f0 + ff) * 1024] = acc;   // coalesced 256B store
        }
    }
}

extern "C" void kernel_launch(void* const* d_in, const int* in_sizes, int n_in,
                              void* d_out, int out_size, void* d_ws, size_t ws_size,
                              hipStream_t stream) {
    const float* x    = (const float*)d_in[0];
    const float* w    = (const float*)d_in[1];
    const float* bias = (const float*)d_in[2];
    // d_in[3] = fm (int32) -- analytic, unused.
    float* out = (float*)d_out;

    dim3 grid(16 * (2048 / BTILE));   // 1024 blocks
    dim3 block(256);
    hypercube_kernel<<<grid, block, 0, stream>>>(x, w, bias, out);
}